// Round 4
// baseline (338.455 us; speedup 1.0000x reference)
//
#include <hip/hip_runtime.h>

#define BATCH   4096
#define SLOTS   26
#define MAX_NNZ 10
#define EMB     64
#define ROWS    (BATCH * SLOTS)     // 106,496 output rows
#define RPW     2                   // rows per wave-slot (32 lanes/row, float2 frags)
#define NSLOTB  (ROWS / RPW)        // 53,248 wave-slots total
#define NBLK    512
#define WPB     4
#define NWAVE   (NBLK * WPB)        // 2048 waves
#define NS      (NSLOTB / NWAVE)    // 26 slots per wave (exact)
#define PAIRS   (NS / 2)            // 13 loop iterations

typedef float floatx2 __attribute__((ext_vector_type(2)));
typedef int   intx2   __attribute__((ext_vector_type(2)));

// 2-deep register-destination gather pipeline, compiler-managed waits ONLY.
// Per wave: vA holds slot s gathers in flight while vB holds slot s+1;
// keys are double-buffered (krA/krB) and loaded TWO slots ahead, issued
// BEFORE the younger gathers so the compiler's counted vmcnt wait for keys
// leaves the in-flight gathers outstanding. No LDS, no barriers, no asm.
__global__ __launch_bounds__(256) void emb_fwd_kernel(
    const int*   __restrict__ keys,   // [ROWS, MAX_NNZ]
    const int*   __restrict__ mask,   // [ROWS, MAX_NNZ] (0/1)
    const float* __restrict__ table,  // [VOCAB, EMB]
    float*       __restrict__ out)    // [ROWS, EMB]
{
    const int lane = threadIdx.x & 63;
    const int gw   = (blockIdx.x * blockDim.x + threadIdx.x) >> 6;  // 0..2047
    const int half = lane >> 5;      // which of the 2 rows in this slot
    const int e2   = lane & 31;      // float2 index within the 64-float row

    const char* tb = (const char*)table;
    const floatx2 r0 = *(const floatx2*)(tb + e2 * 8);   // row-0 frag (L1-hot)

    intx2 krA[5], mrA[5], krB[5], mrB[5];   // keys/mask in flight (8B-aligned 40B rows)
    unsigned off[MAX_NNZ];                  // transient converted offsets
    floatx2  vA[MAX_NNZ], vB[MAX_NNZ];      // gather destinations (2-deep)
    float cntA, cntB;

    auto kload = [&](intx2* kr, intx2* mr, int s) {
        const size_t r = (size_t)(gw + s * NWAVE) * RPW + half;
        const intx2* kp = (const intx2*)(keys + r * MAX_NNZ);
        const intx2* mp = (const intx2*)(mask + r * MAX_NNZ);
#pragma unroll
        for (int t = 0; t < 5; ++t) { kr[t] = kp[t]; mr[t] = mp[t]; }
    };

    auto conv = [&](const intx2* kr, const intx2* mr, float& cnt) {
        int c = 0;
#pragma unroll
        for (int j = 0; j < MAX_NNZ; ++j) {
            int k = kr[j >> 1][j & 1];
            int m = mr[j >> 1][j & 1];
            c += (m != 0);
            off[j] = ((unsigned)(m != 0 ? k : 0)) << 8;   // masked -> row 0
        }
        cnt = (float)c;
    };

    auto gissue = [&](floatx2* v) {
#pragma unroll
        for (int j = 0; j < MAX_NNZ; ++j)
            v[j] = *(const floatx2*)(tb + (off[j] + (unsigned)(e2 * 8)));
    };

    auto finish = [&](const floatx2* v, float cnt, int s) {
        floatx2 acc = (floatx2){0.f, 0.f};
#pragma unroll
        for (int j = 0; j < MAX_NNZ; ++j) acc += v[j];
        float c = cnt > 0.f ? cnt : 1.f;
        floatx2 res = (acc - (10.f - cnt) * r0) * (1.0f / c);
        const size_t r = (size_t)(gw + s * NWAVE) * RPW + half;
        __builtin_nontemporal_store(res, (floatx2*)(out + r * EMB + e2 * 2));
    };

    // ---- prologue: establish {vA=slot0, vB=slot1 in flight; krA=keys(2), krB=keys(3) in flight} ----
    kload(krA, mrA, 0);
    conv(krA, mrA, cntA);          // compiler waits keys(0) only
    kload(krB, mrB, 1);
    gissue(vA);                    // slot 0 gathers issued
    conv(krB, mrB, cntB);          // compiler counted wait: gathers(vA) stay in flight
    kload(krA, mrA, 2);
    gissue(vB);                    // slot 1 gathers issued
    kload(krB, mrB, 3);

    // ---- steady-state: 13 pairs ----
#pragma unroll 1
    for (int t = 0; t < PAIRS; ++t) {
        const int a = 2 * t, b = 2 * t + 1;

        // A half: consume slot a, refill vA with slot a+2
        finish(vA, cntA, a);       // waits vA; vB + krA/krB loads stay in flight
        if (a + 2 < NS) { conv(krA, mrA, cntA); gissue(vA); }  // slot a+2
        if (a + 4 < NS) kload(krA, mrA, a + 4);

        // B half: consume slot b, refill vB with slot b+2
        finish(vB, cntB, b);
        if (b + 2 < NS) { conv(krB, mrB, cntB); gissue(vB); }  // slot b+2
        if (b + 4 < NS) kload(krB, mrB, b + 4);
    }
}

extern "C" void kernel_launch(void* const* d_in, const int* in_sizes, int n_in,
                              void* d_out, int out_size, void* d_ws, size_t ws_size,
                              hipStream_t stream) {
    const int*   keys  = (const int*)d_in[0];
    const int*   mask  = (const int*)d_in[1];
    const float* table = (const float*)d_in[2];
    float*       out   = (float*)d_out;

    emb_fwd_kernel<<<NBLK, 256, 0, stream>>>(keys, mask, table, out);
}